// Round 3
// baseline (856.506 us; speedup 1.0000x reference)
//
#include <hip/hip_runtime.h>
#include <cstdint>
#include <cstddef>

#define N_TOK 16384
#define E_DIM 512
#define C_DIM 8
#define K_CODES 8192
#define LN_EPS 1e-5f

typedef __attribute__((ext_vector_type(8))) short short8;
typedef __attribute__((ext_vector_type(4))) float f32x4;

// ---------- helpers: fp32 -> bf16 round-nearest-even, hi/lo split ----------
__device__ __forceinline__ unsigned short bf16_rn(float x) {
  unsigned u = __float_as_uint(x);
  unsigned r = u + 0x7FFFu + ((u >> 16) & 1u);
  return (unsigned short)(r >> 16);
}
__device__ __forceinline__ float bf16_f(unsigned short h) {
  return __uint_as_float(((unsigned)h) << 16);
}

__device__ __forceinline__ void gload16(const void* g, void* l) {
  __builtin_amdgcn_global_load_lds(
      (const __attribute__((address_space(1))) void*)g,
      (__attribute__((address_space(3))) void*)l, 16, 0, 0);
}

// ---------- pack bodies (fragment-linear hi/lo bf16) ----------
// A (M x 512 row-major): t = (mf*16 + kt)*64 + l ; entry = A[mf*16+(l&15)][kt*32+(l>>4)*8 + j]
__device__ __forceinline__ void pack_a_body(const float* __restrict__ A,
    unsigned short* __restrict__ hi, unsigned short* __restrict__ lo, int t) {
  int l = t & 63;
  int kt = (t >> 6) & 15;
  int mf = t >> 10;
  const float* src = A + (size_t)(mf * 16 + (l & 15)) * 512 + kt * 32 + (l >> 4) * 8;
  float4 x0 = *(const float4*)src;
  float4 x1 = *(const float4*)(src + 4);
  float xs[8] = {x0.x, x0.y, x0.z, x0.w, x1.x, x1.y, x1.z, x1.w};
  unsigned hw[4], lw[4];
#pragma unroll
  for (int p = 0; p < 4; ++p) {
    float a = xs[2 * p], b = xs[2 * p + 1];
    unsigned short ha = bf16_rn(a), hb = bf16_rn(b);
    unsigned short la = bf16_rn(a - bf16_f(ha)), lb = bf16_rn(b - bf16_f(hb));
    hw[p] = (unsigned)ha | ((unsigned)hb << 16);
    lw[p] = (unsigned)la | ((unsigned)lb << 16);
  }
  uint4 hv; hv.x = hw[0]; hv.y = hw[1]; hv.z = hw[2]; hv.w = hw[3];
  uint4 lv; lv.x = lw[0]; lv.y = lw[1]; lv.z = lw[2]; lv.w = lw[3];
  ((uint4*)hi)[t] = hv;
  ((uint4*)lo)[t] = lv;
}

// B (512 x 512 K x N row-major): t = (nf*16 + kt)*64 + l ; entry = B[kt*32+(l>>4)*8+j][nf*16+(l&15)]
__device__ __forceinline__ void pack_b_body(const float* __restrict__ B,
    unsigned short* __restrict__ hi, unsigned short* __restrict__ lo, int t) {
  int l = t & 63;
  int kt = (t >> 6) & 15;
  int nf = t >> 10;
  int col = nf * 16 + (l & 15);
  int krow = kt * 32 + (l >> 4) * 8;
  unsigned hw[4], lw[4];
#pragma unroll
  for (int p = 0; p < 4; ++p) {
    float a = B[(size_t)(krow + 2 * p) * 512 + col];
    float b = B[(size_t)(krow + 2 * p + 1) * 512 + col];
    unsigned short ha = bf16_rn(a), hb = bf16_rn(b);
    unsigned short la = bf16_rn(a - bf16_f(ha)), lb = bf16_rn(b - bf16_f(hb));
    hw[p] = (unsigned)ha | ((unsigned)hb << 16);
    lw[p] = (unsigned)la | ((unsigned)lb << 16);
  }
  uint4 hv; hv.x = hw[0]; hv.y = hw[1]; hv.z = hw[2]; hv.w = hw[3];
  uint4 lv; lv.x = lw[0]; lv.y = lw[1]; lv.z = lw[2]; lv.w = lw[3];
  ((uint4*)hi)[t] = hv;
  ((uint4*)lo)[t] = lv;
}

// ---------- fused prep: pack A1 | pack B1 | pack B2 | ne | proj_out1 -> packed A2 ----------
__global__ __launch_bounds__(256) void prep(const float* __restrict__ features,
    const float* __restrict__ W1_in, const float* __restrict__ W2_out,
    const float* __restrict__ emb,
    const float* __restrict__ W1_out, const float* __restrict__ b1_out,
    unsigned short* __restrict__ A1h, unsigned short* __restrict__ A1l,
    unsigned short* __restrict__ B1h, unsigned short* __restrict__ B1l,
    unsigned short* __restrict__ B2h, unsigned short* __restrict__ B2l,
    unsigned short* __restrict__ A2h, unsigned short* __restrict__ A2l,
    float* __restrict__ ne) {
  int bid = blockIdx.x;
  int tid = threadIdx.x;
  if (bid < 4096) {
    pack_a_body(features, A1h, A1l, bid * 256 + tid);
  } else if (bid < 4224) {
    pack_b_body(W1_in, B1h, B1l, (bid - 4096) * 256 + tid);
  } else if (bid < 4352) {
    pack_b_body(W2_out, B2h, B2l, (bid - 4224) * 256 + tid);
  } else if (bid < 4384) {
    int k = (bid - 4352) * 256 + tid;
    const float* e = emb + (size_t)k * C_DIM;
    float s = 0.f;
#pragma unroll
    for (int c = 0; c < C_DIM; ++c) s = fmaf(e[c], e[c], s);
    ne[k] = s;
  } else {
    // relu(emb @ W1_out + b1_out) emitted directly in packed hi/lo A-layout
    int mf = bid - 4384;               // 0..511
    int l = tid & 63;
    int kt4 = tid >> 6;                // 0..3
    int k0 = mf * 16 + (l & 15);
    float ev[C_DIM];
#pragma unroll
    for (int c = 0; c < C_DIM; ++c) ev[c] = emb[(size_t)k0 * C_DIM + c];
#pragma unroll
    for (int it = 0; it < 4; ++it) {
      int kt = it * 4 + kt4;
      int e0 = kt * 32 + (l >> 4) * 8;
      float o[8];
      float4 bv0 = *(const float4*)(b1_out + e0);
      float4 bv1 = *(const float4*)(b1_out + e0 + 4);
      o[0] = bv0.x; o[1] = bv0.y; o[2] = bv0.z; o[3] = bv0.w;
      o[4] = bv1.x; o[5] = bv1.y; o[6] = bv1.z; o[7] = bv1.w;
#pragma unroll
      for (int c = 0; c < C_DIM; ++c) {
        float4 w0 = *(const float4*)(W1_out + (size_t)c * E_DIM + e0);
        float4 w1 = *(const float4*)(W1_out + (size_t)c * E_DIM + e0 + 4);
        o[0] = fmaf(ev[c], w0.x, o[0]); o[1] = fmaf(ev[c], w0.y, o[1]);
        o[2] = fmaf(ev[c], w0.z, o[2]); o[3] = fmaf(ev[c], w0.w, o[3]);
        o[4] = fmaf(ev[c], w1.x, o[4]); o[5] = fmaf(ev[c], w1.y, o[5]);
        o[6] = fmaf(ev[c], w1.z, o[6]); o[7] = fmaf(ev[c], w1.w, o[7]);
      }
      unsigned hw[4], lw[4];
#pragma unroll
      for (int p = 0; p < 4; ++p) {
        float a = fmaxf(o[2 * p], 0.f), b = fmaxf(o[2 * p + 1], 0.f);
        unsigned short ha = bf16_rn(a), hb = bf16_rn(b);
        unsigned short la = bf16_rn(a - bf16_f(ha)), lb = bf16_rn(b - bf16_f(hb));
        hw[p] = (unsigned)ha | ((unsigned)hb << 16);
        lw[p] = (unsigned)la | ((unsigned)lb << 16);
      }
      size_t t = ((size_t)mf * 16 + kt) * 64 + l;
      uint4 hv; hv.x = hw[0]; hv.y = hw[1]; hv.z = hw[2]; hv.w = hw[3];
      uint4 lv; lv.x = lw[0]; lv.y = lw[1]; lv.z = lw[2]; lv.w = lw[3];
      ((uint4*)A2h)[t] = hv;
      ((uint4*)A2l)[t] = lv;
    }
  }
}

// ---------- split-bf16 MFMA GEMM, 2-phase pipelined, N=K=512 ----------
// BM=128 BN=128 BK=32, 4 waves (2x2), wave tile 64x64 = 4x4 fragments of 16x16
// acc += Ahi*Bhi + Ahi*Blo + Alo*Bhi in 3 SWEEPS: same-dst MFMAs spaced 16 apart
// (dep-chain break; per-element accumulation order identical -> bit-exact)
template<bool RELU>
__global__ __launch_bounds__(256) void gemm_mfma(const unsigned short* __restrict__ Ah,
    const unsigned short* __restrict__ Al, const unsigned short* __restrict__ Bh,
    const unsigned short* __restrict__ Bl, const float* __restrict__ bias,
    float* __restrict__ C) {
  __shared__ char smem[65536];   // 2 buffers x (Ahi 8K | Alo 8K | Bhi 8K | Blo 8K)
  const int tid = threadIdx.x;
  const int l = tid & 63;
  const int w = tid >> 6;
  const int wm = w >> 1, wn = w & 1;
  const int mblk = blockIdx.y, nblk = blockIdx.x;

  const char* gAh = (const char*)Ah + (((size_t)(mblk * 8 + 2 * w) * 16) * 64 + l) * 16;
  const char* gAl = (const char*)Al + (((size_t)(mblk * 8 + 2 * w) * 16) * 64 + l) * 16;
  const char* gBh = (const char*)Bh + (((size_t)(nblk * 8 + 2 * w) * 16) * 64 + l) * 16;
  const char* gBl = (const char*)Bl + (((size_t)(nblk * 8 + 2 * w) * 16) * 64 + l) * 16;

  f32x4 acc[4][4];
#pragma unroll
  for (int i = 0; i < 4; ++i)
#pragma unroll
    for (int j = 0; j < 4; ++j) acc[i][j] = (f32x4){0.f, 0.f, 0.f, 0.f};

  auto stage = [&](int buf, int kt) {
    char* base = smem + buf * 32768;
    const size_t ko = (size_t)kt * 1024;
    char* dA0 = base + (2 * w) * 1024;            // wave-uniform LDS dests
    char* dA1 = base + 8192 + (2 * w) * 1024;
    char* dB0 = base + 16384 + (2 * w) * 1024;
    char* dB1 = base + 24576 + (2 * w) * 1024;
    gload16(gAh + ko,         dA0);
    gload16(gAh + ko + 16384, dA0 + 1024);
    gload16(gAl + ko,         dA1);
    gload16(gAl + ko + 16384, dA1 + 1024);
    gload16(gBh + ko,         dB0);
    gload16(gBh + ko + 16384, dB0 + 1024);
    gload16(gBl + ko,         dB1);
    gload16(gBl + ko + 16384, dB1 + 1024);
  };

  auto compute = [&](int buf) {
    const char* base = smem + buf * 32768;
    const short8* sAh = (const short8*)(base);
    const short8* sAl = (const short8*)(base + 8192);
    const short8* sBh = (const short8*)(base + 16384);
    const short8* sBl = (const short8*)(base + 24576);
    short8 a_h[4], a_l[4], b_h[4], b_l[4];
#pragma unroll
    for (int i = 0; i < 4; ++i) {
      a_h[i] = sAh[(wm * 4 + i) * 64 + l];
      a_l[i] = sAl[(wm * 4 + i) * 64 + l];
    }
#pragma unroll
    for (int j = 0; j < 4; ++j) {
      b_h[j] = sBh[(wn * 4 + j) * 64 + l];
      b_l[j] = sBl[(wn * 4 + j) * 64 + l];
    }
    // sweep 1: hi*hi for all 16 fragments (no back-to-back same-dst deps)
#pragma unroll
    for (int i = 0; i < 4; ++i)
#pragma unroll
      for (int j = 0; j < 4; ++j)
        acc[i][j] = __builtin_amdgcn_mfma_f32_16x16x32_bf16(a_h[i], b_h[j], acc[i][j], 0, 0, 0);
    // sweep 2: hi*lo
#pragma unroll
    for (int i = 0; i < 4; ++i)
#pragma unroll
      for (int j = 0; j < 4; ++j)
        acc[i][j] = __builtin_amdgcn_mfma_f32_16x16x32_bf16(a_h[i], b_l[j], acc[i][j], 0, 0, 0);
    // sweep 3: lo*hi
#pragma unroll
    for (int i = 0; i < 4; ++i)
#pragma unroll
      for (int j = 0; j < 4; ++j)
        acc[i][j] = __builtin_amdgcn_mfma_f32_16x16x32_bf16(a_l[i], b_h[j], acc[i][j], 0, 0, 0);
  };

  stage(0, 0);
  __syncthreads();
  int cur = 0;
#pragma unroll 1
  for (int kt = 1; kt < 16; ++kt) {
    stage(cur ^ 1, kt);
    compute(cur);
    __syncthreads();
    cur ^= 1;
  }
  compute(cur);

  // epilogue: D col = lane&15, row = (lane>>4)*4 + r
  const int colb = nblk * 128 + wn * 64 + (l & 15);
  const int rowb = mblk * 128 + wm * 64 + ((l >> 4) << 2);
#pragma unroll
  for (int j = 0; j < 4; ++j) {
    float bv = bias[colb + j * 16];
#pragma unroll
    for (int i = 0; i < 4; ++i) {
#pragma unroll
      for (int r = 0; r < 4; ++r) {
        float v = acc[i][j][r] + bv;
        if (RELU) v = fmaxf(v, 0.f);
        C[(size_t)(rowb + i * 16 + r) * 512 + colb + j * 16] = v;
      }
    }
  }
}

// ---------- z = LN(h @ W2_in + b2) over C=8; one wave per token ----------
__global__ __launch_bounds__(256) void zln_kernel(const float* __restrict__ h,
    const float* __restrict__ W2, const float* __restrict__ b2,
    const float* __restrict__ g, const float* __restrict__ b,
    float* __restrict__ z) {
  int token = blockIdx.x * 4 + (threadIdx.x >> 6);
  int lane = threadIdx.x & 63;
  const float* hr = h + (size_t)token * E_DIM;
  float acc[C_DIM];
#pragma unroll
  for (int c = 0; c < C_DIM; ++c) acc[c] = 0.f;
  for (int e = lane; e < E_DIM; e += 64) {
    float hv = hr[e];
    const float* w = W2 + e * C_DIM;
#pragma unroll
    for (int c = 0; c < C_DIM; ++c) acc[c] = fmaf(hv, w[c], acc[c]);
  }
#pragma unroll
  for (int c = 0; c < C_DIM; ++c) {
#pragma unroll
    for (int off = 32; off > 0; off >>= 1) acc[c] += __shfl_down(acc[c], off);
  }
  if (lane == 0) {
    float v[C_DIM]; float mu = 0.f;
#pragma unroll
    for (int c = 0; c < C_DIM; ++c) { v[c] = acc[c] + b2[c]; mu += v[c]; }
    mu *= 0.125f;
    float var = 0.f;
#pragma unroll
    for (int c = 0; c < C_DIM; ++c) { float d = v[c] - mu; var += d * d; }
    var *= 0.125f;
    float inv = 1.0f / sqrtf(var + LN_EPS);
#pragma unroll
    for (int c = 0; c < C_DIM; ++c)
      z[(size_t)token * C_DIM + c] = ((v[c] - mu) * inv) * g[c] + b[c];
  }
}

// ---------- partial argmin: lane=token, code index uniform (scalar loads) ----------
__global__ __launch_bounds__(256) void vq_partial(const float* __restrict__ z,
    const float* __restrict__ emb, const float* __restrict__ ne,
    float* __restrict__ pbest, int* __restrict__ pidx) {
  int chunk = blockIdx.x & 7;                 // 8 chunks of 1024 codes
  int token = (blockIdx.x >> 3) * 256 + threadIdx.x;
  float zv[C_DIM];
#pragma unroll
  for (int c = 0; c < C_DIM; ++c) zv[c] = z[(size_t)token * C_DIM + c];
  float s = 0.f;
#pragma unroll
  for (int c = 0; c < C_DIM; ++c) s = fmaf(zv[c], zv[c], s);
  float best = 3.402823466e38f; int bi = 0;
  int j0 = chunk * 1024;
  for (int j = j0; j < j0 + 1024; ++j) {
    const float* e = emb + (size_t)j * C_DIM;  // uniform address -> s_load
    float p = 0.f;
#pragma unroll
    for (int c = 0; c < C_DIM; ++c) p = fmaf(zv[c], e[c], p);
    float d = fmaf(-2.f, p, s) + ne[j];
    if (d < best) { best = d; bi = j; }        // strict < : first-occurrence argmin
  }
  pbest[chunk * N_TOK + token] = best;
  pidx[chunk * N_TOK + token] = bi;
}

// ---------- combine 8 chunk-partials (ascending chunk keeps first-occurrence) ----------
__global__ void vq_combine(const float* __restrict__ pbest, const int* __restrict__ pidx,
    int* __restrict__ idx_i, float* __restrict__ idxf) {
  int n = blockIdx.x * 256 + threadIdx.x;
  float best = pbest[n]; int bi = pidx[n];
#pragma unroll
  for (int c = 1; c < 8; ++c) {
    float bb = pbest[c * N_TOK + n]; int i2 = pidx[c * N_TOK + n];
    if (bb < best) { best = bb; bi = i2; }
  }
  idx_i[n] = bi;
  idxf[n] = (float)bi;
}

// ---------- fused gather + LayerNorm: q[n] = LN(oc[idx[n]]) ----------
__global__ __launch_bounds__(128) void gather_ln(const float* __restrict__ oc,
    const int* __restrict__ idx_i, const float* __restrict__ gw,
    const float* __restrict__ bw, float* __restrict__ q) {
  int n = blockIdx.x;
  int tid = threadIdx.x;
  int k = idx_i[n];
  const float* r = oc + (size_t)k * E_DIM;
  float4 v = ((const float4*)r)[tid];
  __shared__ float red[4];
  int lane = tid & 63, wid = tid >> 6;
  float sum = v.x + v.y + v.z + v.w;
#pragma unroll
  for (int off = 32; off > 0; off >>= 1) sum += __shfl_xor(sum, off);
  if (lane == 0) red[wid] = sum;
  __syncthreads();
  float mu = (red[0] + red[1]) * (1.0f / 512.0f);
  float4 d;
  d.x = v.x - mu; d.y = v.y - mu; d.z = v.z - mu; d.w = v.w - mu;
  float sq = d.x * d.x + d.y * d.y + d.z * d.z + d.w * d.w;
#pragma unroll
  for (int off = 32; off > 0; off >>= 1) sq += __shfl_xor(sq, off);
  if (lane == 0) red[2 + wid] = sq;
  __syncthreads();
  float var = (red[2] + red[3]) * (1.0f / 512.0f);
  float inv = 1.0f / sqrtf(var + LN_EPS);
  float4 gg = ((const float4*)gw)[tid];
  float4 bb = ((const float4*)bw)[tid];
  float4 o;
  o.x = d.x * inv * gg.x + bb.x;
  o.y = d.y * inv * gg.y + bb.y;
  o.z = d.z * inv * gg.z + bb.z;
  o.w = d.w * inv * gg.w + bb.w;
  ((float4*)(q + (size_t)n * E_DIM))[tid] = o;
}

// ---------- zero the encodings row and plant the 1.0 in one pass ----------
__global__ __launch_bounds__(256) void zero_scatter(const float* __restrict__ idxf,
    float* __restrict__ enc) {
  int n = blockIdx.x;
  int tid = threadIdx.x;
  int k = (int)idxf[n];                         // idxf lives OUTSIDE enc region
  float* row = enc + (size_t)n * K_CODES;
  float4 zv = {0.f, 0.f, 0.f, 0.f};
  int base = tid * 32;
#pragma unroll
  for (int u = 0; u < 8; ++u)
    ((float4*)(row + base + u * 4))[0] = zv;
  if ((k >> 5) == tid) row[k] = 1.0f;           // same-thread ordered overwrite
}

extern "C" void kernel_launch(void* const* d_in, const int* in_sizes, int n_in,
                              void* d_out, int out_size, void* d_ws, size_t ws_size,
                              hipStream_t stream) {
  const float* features = (const float*)d_in[0];
  const float* W1_in  = (const float*)d_in[1];
  const float* b1_in  = (const float*)d_in[2];
  const float* W2_in  = (const float*)d_in[3];
  const float* b2_in  = (const float*)d_in[4];
  const float* ln_in_g = (const float*)d_in[5];
  const float* ln_in_b = (const float*)d_in[6];
  const float* emb    = (const float*)d_in[7];
  const float* W1_out = (const float*)d_in[8];
  const float* b1_out = (const float*)d_in[9];
  const float* W2_out = (const float*)d_in[10];
  const float* b2_out = (const float*)d_in[11];
  const float* ln_out_g = (const float*)d_in[12];
  const float* ln_out_b = (const float*)d_in[13];

  float* q    = (float*)d_out;                       // N*E
  float* idxf = q + (size_t)N_TOK * E_DIM;           // N (as float)
  float* enc  = idxf + N_TOK;                        // N*K one-hot

  // Use the 537 MB encodings region as scratch; zero_scatter happens last.
  float* h     = enc;                        // 16384*512
  float* g     = enc + 12582912;             // 8192*512
  float* z     = enc + 16777216;             // 16384*8
  float* ne    = enc + 16908288;             // 8192
  float* pbest = enc + 16916480;             // 8*16384
  int*   idx_i = (int*)(enc + 17047552);     // 16384
  int*   pidx  = (int*)(enc + 17063936);     // 8*16384
  unsigned short* A1h = (unsigned short*)(enc + 17195008);  // 16384*512 bf16
  unsigned short* A1l = (unsigned short*)(enc + 21389312);
  unsigned short* A2h = (unsigned short*)(enc + 25583616);  // 8192*512 bf16
  unsigned short* A2l = (unsigned short*)(enc + 27680768);
  unsigned short* B1h = (unsigned short*)(enc + 29777920);  // 512*512 bf16
  unsigned short* B1l = (unsigned short*)(enc + 29908992);
  unsigned short* B2h = (unsigned short*)(enc + 30040064);
  unsigned short* B2l = (unsigned short*)(enc + 30171136);

  // 1. fused prep: pack A1 (features), B1 (W1_in), B2 (W2_out), code norms,
  //    and proj_out1 -> packed A2 (all input-only work)
  prep<<<4896, 256, 0, stream>>>(features, W1_in, W2_out, emb, W1_out, b1_out,
                                 A1h, A1l, B1h, B1l, B2h, B2l, A2h, A2l, ne);

  // 2. project_in: h = relu(features @ W1_in + b1)
  dim3 g1(4, N_TOK / 128);
  gemm_mfma<true><<<g1, 256, 0, stream>>>(A1h, A1l, B1h, B1l, b1_in, h);

  // 3. z = LN(h @ W2_in + b2)
  zln_kernel<<<N_TOK / 4, 256, 0, stream>>>(h, W2_in, b2_in, ln_in_g, ln_in_b, z);

  // 4-5. VQ argmin
  vq_partial<<<(N_TOK / 256) * 8, 256, 0, stream>>>(z, emb, ne, pbest, pidx);
  vq_combine<<<N_TOK / 256, 256, 0, stream>>>(pbest, pidx, idx_i, idxf);

  // 6. project_out GEMM over codebook: g = A2 @ W2_out + b2 (unnormalized)
  dim3 g2(4, K_CODES / 128);
  gemm_mfma<false><<<g2, 256, 0, stream>>>(A2h, A2l, B2h, B2l, b2_out, g);

  // 7. q[n] = LN(g[idx[n]]) — fused gather + LayerNorm
  gather_ln<<<N_TOK, 128, 0, stream>>>(g, idx_i, ln_out_g, ln_out_b, q);

  // 8. encodings: zeros + one-hot in a single fill-rate pass
  zero_scatter<<<N_TOK, 256, 0, stream>>>(idxf, enc);
}

// Round 4
// 781.747 us; speedup vs baseline: 1.0956x; 1.0956x over previous
//
#include <hip/hip_runtime.h>
#include <cstdint>
#include <cstddef>

#define N_TOK 16384
#define E_DIM 512
#define C_DIM 8
#define K_CODES 8192
#define LN_EPS 1e-5f

typedef __attribute__((ext_vector_type(8))) short short8;
typedef __attribute__((ext_vector_type(4))) float f32x4;

// ---------- helpers: fp32 -> bf16 round-nearest-even, hi/lo split ----------
__device__ __forceinline__ unsigned short bf16_rn(float x) {
  unsigned u = __float_as_uint(x);
  unsigned r = u + 0x7FFFu + ((u >> 16) & 1u);
  return (unsigned short)(r >> 16);
}
__device__ __forceinline__ float bf16_f(unsigned short h) {
  return __uint_as_float(((unsigned)h) << 16);
}

__device__ __forceinline__ void gload16(const void* g, void* l) {
  __builtin_amdgcn_global_load_lds(
      (const __attribute__((address_space(1))) void*)g,
      (__attribute__((address_space(3))) void*)l, 16, 0, 0);
}

// ---------- pack bodies (fragment-linear hi/lo bf16) ----------
// A (M x 512 row-major): t = (mf*16 + kt)*64 + l ; entry = A[mf*16+(l&15)][kt*32+(l>>4)*8 + j]
__device__ __forceinline__ void pack_a_body(const float* __restrict__ A,
    unsigned short* __restrict__ hi, unsigned short* __restrict__ lo, int t) {
  int l = t & 63;
  int kt = (t >> 6) & 15;
  int mf = t >> 10;
  const float* src = A + (size_t)(mf * 16 + (l & 15)) * 512 + kt * 32 + (l >> 4) * 8;
  float4 x0 = *(const float4*)src;
  float4 x1 = *(const float4*)(src + 4);
  float xs[8] = {x0.x, x0.y, x0.z, x0.w, x1.x, x1.y, x1.z, x1.w};
  unsigned hw[4], lw[4];
#pragma unroll
  for (int p = 0; p < 4; ++p) {
    float a = xs[2 * p], b = xs[2 * p + 1];
    unsigned short ha = bf16_rn(a), hb = bf16_rn(b);
    unsigned short la = bf16_rn(a - bf16_f(ha)), lb = bf16_rn(b - bf16_f(hb));
    hw[p] = (unsigned)ha | ((unsigned)hb << 16);
    lw[p] = (unsigned)la | ((unsigned)lb << 16);
  }
  uint4 hv; hv.x = hw[0]; hv.y = hw[1]; hv.z = hw[2]; hv.w = hw[3];
  uint4 lv; lv.x = lw[0]; lv.y = lw[1]; lv.z = lw[2]; lv.w = lw[3];
  ((uint4*)hi)[t] = hv;
  ((uint4*)lo)[t] = lv;
}

// B (512 x 512 K x N row-major): t = (nf*16 + kt)*64 + l ; entry = B[kt*32+(l>>4)*8+j][nf*16+(l&15)]
__device__ __forceinline__ void pack_b_body(const float* __restrict__ B,
    unsigned short* __restrict__ hi, unsigned short* __restrict__ lo, int t) {
  int l = t & 63;
  int kt = (t >> 6) & 15;
  int nf = t >> 10;
  int col = nf * 16 + (l & 15);
  int krow = kt * 32 + (l >> 4) * 8;
  unsigned hw[4], lw[4];
#pragma unroll
  for (int p = 0; p < 4; ++p) {
    float a = B[(size_t)(krow + 2 * p) * 512 + col];
    float b = B[(size_t)(krow + 2 * p + 1) * 512 + col];
    unsigned short ha = bf16_rn(a), hb = bf16_rn(b);
    unsigned short la = bf16_rn(a - bf16_f(ha)), lb = bf16_rn(b - bf16_f(hb));
    hw[p] = (unsigned)ha | ((unsigned)hb << 16);
    lw[p] = (unsigned)la | ((unsigned)lb << 16);
  }
  uint4 hv; hv.x = hw[0]; hv.y = hw[1]; hv.z = hw[2]; hv.w = hw[3];
  uint4 lv; lv.x = lw[0]; lv.y = lw[1]; lv.z = lw[2]; lv.w = lw[3];
  ((uint4*)hi)[t] = hv;
  ((uint4*)lo)[t] = lv;
}

// ---------- fused prep: pack A1 | pack B1 | pack B2 | ne | proj_out1 -> packed A2 ----------
__global__ __launch_bounds__(256) void prep(const float* __restrict__ features,
    const float* __restrict__ W1_in, const float* __restrict__ W2_out,
    const float* __restrict__ emb,
    const float* __restrict__ W1_out, const float* __restrict__ b1_out,
    unsigned short* __restrict__ A1h, unsigned short* __restrict__ A1l,
    unsigned short* __restrict__ B1h, unsigned short* __restrict__ B1l,
    unsigned short* __restrict__ B2h, unsigned short* __restrict__ B2l,
    unsigned short* __restrict__ A2h, unsigned short* __restrict__ A2l,
    float* __restrict__ ne) {
  int bid = blockIdx.x;
  int tid = threadIdx.x;
  if (bid < 4096) {
    pack_a_body(features, A1h, A1l, bid * 256 + tid);
  } else if (bid < 4224) {
    pack_b_body(W1_in, B1h, B1l, (bid - 4096) * 256 + tid);
  } else if (bid < 4352) {
    pack_b_body(W2_out, B2h, B2l, (bid - 4224) * 256 + tid);
  } else if (bid < 4384) {
    int k = (bid - 4352) * 256 + tid;
    const float* e = emb + (size_t)k * C_DIM;
    float s = 0.f;
#pragma unroll
    for (int c = 0; c < C_DIM; ++c) s = fmaf(e[c], e[c], s);
    ne[k] = s;
  } else {
    // relu(emb @ W1_out + b1_out) emitted directly in packed hi/lo A-layout
    int mf = bid - 4384;               // 0..511
    int l = tid & 63;
    int kt4 = tid >> 6;                // 0..3
    int k0 = mf * 16 + (l & 15);
    float ev[C_DIM];
#pragma unroll
    for (int c = 0; c < C_DIM; ++c) ev[c] = emb[(size_t)k0 * C_DIM + c];
#pragma unroll
    for (int it = 0; it < 4; ++it) {
      int kt = it * 4 + kt4;
      int e0 = kt * 32 + (l >> 4) * 8;
      float o[8];
      float4 bv0 = *(const float4*)(b1_out + e0);
      float4 bv1 = *(const float4*)(b1_out + e0 + 4);
      o[0] = bv0.x; o[1] = bv0.y; o[2] = bv0.z; o[3] = bv0.w;
      o[4] = bv1.x; o[5] = bv1.y; o[6] = bv1.z; o[7] = bv1.w;
#pragma unroll
      for (int c = 0; c < C_DIM; ++c) {
        float4 w0 = *(const float4*)(W1_out + (size_t)c * E_DIM + e0);
        float4 w1 = *(const float4*)(W1_out + (size_t)c * E_DIM + e0 + 4);
        o[0] = fmaf(ev[c], w0.x, o[0]); o[1] = fmaf(ev[c], w0.y, o[1]);
        o[2] = fmaf(ev[c], w0.z, o[2]); o[3] = fmaf(ev[c], w0.w, o[3]);
        o[4] = fmaf(ev[c], w1.x, o[4]); o[5] = fmaf(ev[c], w1.y, o[5]);
        o[6] = fmaf(ev[c], w1.z, o[6]); o[7] = fmaf(ev[c], w1.w, o[7]);
      }
      unsigned hw[4], lw[4];
#pragma unroll
      for (int p = 0; p < 4; ++p) {
        float a = fmaxf(o[2 * p], 0.f), b = fmaxf(o[2 * p + 1], 0.f);
        unsigned short ha = bf16_rn(a), hb = bf16_rn(b);
        unsigned short la = bf16_rn(a - bf16_f(ha)), lb = bf16_rn(b - bf16_f(hb));
        hw[p] = (unsigned)ha | ((unsigned)hb << 16);
        lw[p] = (unsigned)la | ((unsigned)lb << 16);
      }
      size_t t = ((size_t)mf * 16 + kt) * 64 + l;
      uint4 hv; hv.x = hw[0]; hv.y = hw[1]; hv.z = hw[2]; hv.w = hw[3];
      uint4 lv; lv.x = lw[0]; lv.y = lw[1]; lv.z = lw[2]; lv.w = lw[3];
      ((uint4*)A2h)[t] = hv;
      ((uint4*)A2l)[t] = lv;
    }
  }
}

// ---------- split-bf16 MFMA GEMM, 2-phase pipelined, N=K=512 ----------
// BM=128 BN=128 BK=32, 4 waves (2x2), wave tile 64x64 = 4x4 fragments of 16x16
// acc += Ahi*Bhi + Ahi*Blo + Alo*Bhi in 3 SWEEPS: same-dst MFMAs spaced 16 apart
template<bool RELU>
__global__ __launch_bounds__(256) void gemm_mfma(const unsigned short* __restrict__ Ah,
    const unsigned short* __restrict__ Al, const unsigned short* __restrict__ Bh,
    const unsigned short* __restrict__ Bl, const float* __restrict__ bias,
    float* __restrict__ C) {
  __shared__ char smem[65536];   // 2 buffers x (Ahi 8K | Alo 8K | Bhi 8K | Blo 8K)
  const int tid = threadIdx.x;
  const int l = tid & 63;
  const int w = tid >> 6;
  const int wm = w >> 1, wn = w & 1;
  const int mblk = blockIdx.y, nblk = blockIdx.x;

  const char* gAh = (const char*)Ah + (((size_t)(mblk * 8 + 2 * w) * 16) * 64 + l) * 16;
  const char* gAl = (const char*)Al + (((size_t)(mblk * 8 + 2 * w) * 16) * 64 + l) * 16;
  const char* gBh = (const char*)Bh + (((size_t)(nblk * 8 + 2 * w) * 16) * 64 + l) * 16;
  const char* gBl = (const char*)Bl + (((size_t)(nblk * 8 + 2 * w) * 16) * 64 + l) * 16;

  f32x4 acc[4][4];
#pragma unroll
  for (int i = 0; i < 4; ++i)
#pragma unroll
    for (int j = 0; j < 4; ++j) acc[i][j] = (f32x4){0.f, 0.f, 0.f, 0.f};

  auto stage = [&](int buf, int kt) {
    char* base = smem + buf * 32768;
    const size_t ko = (size_t)kt * 1024;
    char* dA0 = base + (2 * w) * 1024;            // wave-uniform LDS dests
    char* dA1 = base + 8192 + (2 * w) * 1024;
    char* dB0 = base + 16384 + (2 * w) * 1024;
    char* dB1 = base + 24576 + (2 * w) * 1024;
    gload16(gAh + ko,         dA0);
    gload16(gAh + ko + 16384, dA0 + 1024);
    gload16(gAl + ko,         dA1);
    gload16(gAl + ko + 16384, dA1 + 1024);
    gload16(gBh + ko,         dB0);
    gload16(gBh + ko + 16384, dB0 + 1024);
    gload16(gBl + ko,         dB1);
    gload16(gBl + ko + 16384, dB1 + 1024);
  };

  auto compute = [&](int buf) {
    const char* base = smem + buf * 32768;
    const short8* sAh = (const short8*)(base);
    const short8* sAl = (const short8*)(base + 8192);
    const short8* sBh = (const short8*)(base + 16384);
    const short8* sBl = (const short8*)(base + 24576);
    short8 a_h[4], a_l[4], b_h[4], b_l[4];
#pragma unroll
    for (int i = 0; i < 4; ++i) {
      a_h[i] = sAh[(wm * 4 + i) * 64 + l];
      a_l[i] = sAl[(wm * 4 + i) * 64 + l];
    }
#pragma unroll
    for (int j = 0; j < 4; ++j) {
      b_h[j] = sBh[(wn * 4 + j) * 64 + l];
      b_l[j] = sBl[(wn * 4 + j) * 64 + l];
    }
    // sweep 1: hi*hi for all 16 fragments (no back-to-back same-dst deps)
#pragma unroll
    for (int i = 0; i < 4; ++i)
#pragma unroll
      for (int j = 0; j < 4; ++j)
        acc[i][j] = __builtin_amdgcn_mfma_f32_16x16x32_bf16(a_h[i], b_h[j], acc[i][j], 0, 0, 0);
    // sweep 2: hi*lo
#pragma unroll
    for (int i = 0; i < 4; ++i)
#pragma unroll
      for (int j = 0; j < 4; ++j)
        acc[i][j] = __builtin_amdgcn_mfma_f32_16x16x32_bf16(a_h[i], b_l[j], acc[i][j], 0, 0, 0);
    // sweep 3: lo*hi
#pragma unroll
    for (int i = 0; i < 4; ++i)
#pragma unroll
      for (int j = 0; j < 4; ++j)
        acc[i][j] = __builtin_amdgcn_mfma_f32_16x16x32_bf16(a_l[i], b_h[j], acc[i][j], 0, 0, 0);
  };

  stage(0, 0);
  __syncthreads();
  int cur = 0;
#pragma unroll 1
  for (int kt = 1; kt < 16; ++kt) {
    stage(cur ^ 1, kt);
    compute(cur);
    __syncthreads();
    cur ^= 1;
  }
  compute(cur);

  // epilogue: D col = lane&15, row = (lane>>4)*4 + r
  const int colb = nblk * 128 + wn * 64 + (l & 15);
  const int rowb = mblk * 128 + wm * 64 + ((l >> 4) << 2);
#pragma unroll
  for (int j = 0; j < 4; ++j) {
    float bv = bias[colb + j * 16];
#pragma unroll
    for (int i = 0; i < 4; ++i) {
#pragma unroll
      for (int r = 0; r < 4; ++r) {
        float v = acc[i][j][r] + bv;
        if (RELU) v = fmaxf(v, 0.f);
        C[(size_t)(rowb + i * 16 + r) * 512 + colb + j * 16] = v;
      }
    }
  }
}

// ---------- z = LN(h @ W2_in + b2) over C=8; one wave per token ----------
__global__ __launch_bounds__(256) void zln_kernel(const float* __restrict__ h,
    const float* __restrict__ W2, const float* __restrict__ b2,
    const float* __restrict__ g, const float* __restrict__ b,
    float* __restrict__ z) {
  int token = blockIdx.x * 4 + (threadIdx.x >> 6);
  int lane = threadIdx.x & 63;
  const float* hr = h + (size_t)token * E_DIM;
  float acc[C_DIM];
#pragma unroll
  for (int c = 0; c < C_DIM; ++c) acc[c] = 0.f;
  for (int e = lane; e < E_DIM; e += 64) {
    float hv = hr[e];
    const float* w = W2 + e * C_DIM;
#pragma unroll
    for (int c = 0; c < C_DIM; ++c) acc[c] = fmaf(hv, w[c], acc[c]);
  }
#pragma unroll
  for (int c = 0; c < C_DIM; ++c) {
#pragma unroll
    for (int off = 32; off > 0; off >>= 1) acc[c] += __shfl_down(acc[c], off);
  }
  if (lane == 0) {
    float v[C_DIM]; float mu = 0.f;
#pragma unroll
    for (int c = 0; c < C_DIM; ++c) { v[c] = acc[c] + b2[c]; mu += v[c]; }
    mu *= 0.125f;
    float var = 0.f;
#pragma unroll
    for (int c = 0; c < C_DIM; ++c) { float d = v[c] - mu; var += d * d; }
    var *= 0.125f;
    float inv = 1.0f / sqrtf(var + LN_EPS);
#pragma unroll
    for (int c = 0; c < C_DIM; ++c)
      z[(size_t)token * C_DIM + c] = ((v[c] - mu) * inv) * g[c] + b[c];
  }
}

// ---------- partial argmin: lane=token, code index uniform (scalar loads) ----------
__global__ __launch_bounds__(256) void vq_partial(const float* __restrict__ z,
    const float* __restrict__ emb, const float* __restrict__ ne,
    float* __restrict__ pbest, int* __restrict__ pidx) {
  int chunk = blockIdx.x & 7;                 // 8 chunks of 1024 codes
  int token = (blockIdx.x >> 3) * 256 + threadIdx.x;
  float zv[C_DIM];
#pragma unroll
  for (int c = 0; c < C_DIM; ++c) zv[c] = z[(size_t)token * C_DIM + c];
  float s = 0.f;
#pragma unroll
  for (int c = 0; c < C_DIM; ++c) s = fmaf(zv[c], zv[c], s);
  float best = 3.402823466e38f; int bi = 0;
  int j0 = chunk * 1024;
  for (int j = j0; j < j0 + 1024; ++j) {
    const float* e = emb + (size_t)j * C_DIM;  // uniform address -> s_load
    float p = 0.f;
#pragma unroll
    for (int c = 0; c < C_DIM; ++c) p = fmaf(zv[c], e[c], p);
    float d = fmaf(-2.f, p, s) + ne[j];
    if (d < best) { best = d; bi = j; }        // strict < : first-occurrence argmin
  }
  pbest[chunk * N_TOK + token] = best;
  pidx[chunk * N_TOK + token] = bi;
}

// ---------- combine 8 chunk-partials (ascending chunk keeps first-occurrence) ----------
__global__ void vq_combine(const float* __restrict__ pbest, const int* __restrict__ pidx,
    int* __restrict__ idx_i, float* __restrict__ idxf) {
  int n = blockIdx.x * 256 + threadIdx.x;
  float best = pbest[n]; int bi = pidx[n];
#pragma unroll
  for (int c = 1; c < 8; ++c) {
    float bb = pbest[c * N_TOK + n]; int i2 = pidx[c * N_TOK + n];
    if (bb < best) { best = bb; bi = i2; }
  }
  idx_i[n] = bi;
  idxf[n] = (float)bi;
}

// ---------- fused gather + LayerNorm: q[n] = LN(oc[idx[n]]) ----------
__global__ __launch_bounds__(128) void gather_ln(const float* __restrict__ oc,
    const int* __restrict__ idx_i, const float* __restrict__ gw,
    const float* __restrict__ bw, float* __restrict__ q) {
  int n = blockIdx.x;
  int tid = threadIdx.x;
  int k = idx_i[n];
  const float* r = oc + (size_t)k * E_DIM;
  float4 v = ((const float4*)r)[tid];
  __shared__ float red[4];
  int lane = tid & 63, wid = tid >> 6;
  float sum = v.x + v.y + v.z + v.w;
#pragma unroll
  for (int off = 32; off > 0; off >>= 1) sum += __shfl_xor(sum, off);
  if (lane == 0) red[wid] = sum;
  __syncthreads();
  float mu = (red[0] + red[1]) * (1.0f / 512.0f);
  float4 d;
  d.x = v.x - mu; d.y = v.y - mu; d.z = v.z - mu; d.w = v.w - mu;
  float sq = d.x * d.x + d.y * d.y + d.z * d.z + d.w * d.w;
#pragma unroll
  for (int off = 32; off > 0; off >>= 1) sq += __shfl_xor(sq, off);
  if (lane == 0) red[2 + wid] = sq;
  __syncthreads();
  float var = (red[2] + red[3]) * (1.0f / 512.0f);
  float inv = 1.0f / sqrtf(var + LN_EPS);
  float4 gg = ((const float4*)gw)[tid];
  float4 bb = ((const float4*)bw)[tid];
  float4 o;
  o.x = d.x * inv * gg.x + bb.x;
  o.y = d.y * inv * gg.y + bb.y;
  o.z = d.z * inv * gg.z + bb.z;
  o.w = d.w * inv * gg.w + bb.w;
  ((float4*)(q + (size_t)n * E_DIM))[tid] = o;
}

// ---------- zero the encodings row and plant the 1.0, COALESCED ----------
// lane-interleaved: instruction u writes float4s [u*256 .. u*256+255] across the
// wave -> consecutive lanes hit consecutive 16B (1KB/wave/instr, fill-rate).
__global__ __launch_bounds__(256) void zero_scatter(const float* __restrict__ idxf,
    float* __restrict__ enc) {
  int n = blockIdx.x;
  int tid = threadIdx.x;
  int k = (int)idxf[n];                         // idxf lives OUTSIDE enc region
  float* row = enc + (size_t)n * K_CODES;       // 8192 floats = 2048 float4
  float4 zv = {0.f, 0.f, 0.f, 0.f};
#pragma unroll
  for (int u = 0; u < 8; ++u)
    ((float4*)row)[u * 256 + tid] = zv;
  // float4 (k>>2) was zeroed by thread ((k>>2)&255) in pass ((k>>2)>>8);
  // same-thread program order makes this overwrite safe.
  if (((k >> 2) & 255) == tid) row[k] = 1.0f;
}

extern "C" void kernel_launch(void* const* d_in, const int* in_sizes, int n_in,
                              void* d_out, int out_size, void* d_ws, size_t ws_size,
                              hipStream_t stream) {
  const float* features = (const float*)d_in[0];
  const float* W1_in  = (const float*)d_in[1];
  const float* b1_in  = (const float*)d_in[2];
  const float* W2_in  = (const float*)d_in[3];
  const float* b2_in  = (const float*)d_in[4];
  const float* ln_in_g = (const float*)d_in[5];
  const float* ln_in_b = (const float*)d_in[6];
  const float* emb    = (const float*)d_in[7];
  const float* W1_out = (const float*)d_in[8];
  const float* b1_out = (const float*)d_in[9];
  const float* W2_out = (const float*)d_in[10];
  const float* b2_out = (const float*)d_in[11];
  const float* ln_out_g = (const float*)d_in[12];
  const float* ln_out_b = (const float*)d_in[13];

  float* q    = (float*)d_out;                       // N*E
  float* idxf = q + (size_t)N_TOK * E_DIM;           // N (as float)
  float* enc  = idxf + N_TOK;                        // N*K one-hot

  // Use the 537 MB encodings region as scratch; zero_scatter happens last.
  float* h     = enc;                        // 16384*512
  float* g     = enc + 12582912;             // 8192*512
  float* z     = enc + 16777216;             // 16384*8
  float* ne    = enc + 16908288;             // 8192
  float* pbest = enc + 16916480;             // 8*16384
  int*   idx_i = (int*)(enc + 17047552);     // 16384
  int*   pidx  = (int*)(enc + 17063936);     // 8*16384
  unsigned short* A1h = (unsigned short*)(enc + 17195008);  // 16384*512 bf16
  unsigned short* A1l = (unsigned short*)(enc + 21389312);
  unsigned short* A2h = (unsigned short*)(enc + 25583616);  // 8192*512 bf16
  unsigned short* A2l = (unsigned short*)(enc + 27680768);
  unsigned short* B1h = (unsigned short*)(enc + 29777920);  // 512*512 bf16
  unsigned short* B1l = (unsigned short*)(enc + 29908992);
  unsigned short* B2h = (unsigned short*)(enc + 30040064);
  unsigned short* B2l = (unsigned short*)(enc + 30171136);

  // 1. fused prep: pack A1 (features), B1 (W1_in), B2 (W2_out), code norms,
  //    and proj_out1 -> packed A2 (all input-only work)
  prep<<<4896, 256, 0, stream>>>(features, W1_in, W2_out, emb, W1_out, b1_out,
                                 A1h, A1l, B1h, B1l, B2h, B2l, A2h, A2l, ne);

  // 2. project_in: h = relu(features @ W1_in + b1)
  dim3 g1(4, N_TOK / 128);
  gemm_mfma<true><<<g1, 256, 0, stream>>>(A1h, A1l, B1h, B1l, b1_in, h);

  // 3. z = LN(h @ W2_in + b2)
  zln_kernel<<<N_TOK / 4, 256, 0, stream>>>(h, W2_in, b2_in, ln_in_g, ln_in_b, z);

  // 4-5. VQ argmin
  vq_partial<<<(N_TOK / 256) * 8, 256, 0, stream>>>(z, emb, ne, pbest, pidx);
  vq_combine<<<N_TOK / 256, 256, 0, stream>>>(pbest, pidx, idx_i, idxf);

  // 6. project_out GEMM over codebook: g = A2 @ W2_out + b2 (unnormalized)
  dim3 g2(4, K_CODES / 128);
  gemm_mfma<false><<<g2, 256, 0, stream>>>(A2h, A2l, B2h, B2l, b2_out, g);

  // 7. q[n] = LN(g[idx[n]]) — fused gather + LayerNorm
  gather_ln<<<N_TOK, 128, 0, stream>>>(g, idx_i, ln_out_g, ln_out_b, q);

  // 8. encodings: zeros + one-hot in a single coalesced fill-rate pass
  zero_scatter<<<N_TOK, 256, 0, stream>>>(idxf, enc);
}